// Round 13
// baseline (269.734 us; speedup 1.0000x reference)
//
#include <hip/hip_runtime.h>
#include <limits.h>

#define THREADS 256
#define GRID_BLOCKS 896

typedef int vi4 __attribute__((ext_vector_type(4)));

__device__ __forceinline__ float clamp8f(float q) { return fminf(fmaxf(q, -128.0f), 127.0f); }
__device__ __forceinline__ float sc_from_bits(unsigned b) {
  return fmaxf(__uint_as_float(b) / 127.0f, 1e-8f);
}
__device__ __forceinline__ signed char q8(float v, float s) {
  return (signed char)(int)clamp8f(rintf(v / s));
}

// ===== r13: absorb k_quant into k_ct (-> k_ct2). Quantize phase (qx 2 slices/block via LDS
// transpose + qw ride-along t<64, 57344=896*64 exact) runs FIRST in k_ct2 using IS[0..3] from
// the k_pre boundary; X8/W cross blocks via the r12-PROVEN agent-store -> gbar(B0) -> plain-load
// pattern (A2p lifecycle identical). 2 launches total. Barriers now B0..B6 @128..1088.
// Session ledger: r1 coop-launch not capturable; r2 acquire-poll = L2 maintenance storm;
// r3 fence-free barrier works; r4 cv1-fusion 246.9 (reproduced r11 249.8); r5/r7 VGPR-capped
// fronts spill; r6/r8/r9 deconfound -> cv1-r4 3-barrier beats cv1-r5 by ~10us; r12 conv1+conv2
// merge, identity-from-registers, IDI eliminated -> 239.2 BEST (k_ct 113us, VGPR 64).
// Scalar slots: [0] amax_x [1] amax_w1 [2] amax_w2 [3] amax_wid
// [4] maxabs_h1 [5] maxabs_id [6] maxabs_h2 [7] max_y2(rf) [11] amax_sum
// Grid barriers (zeroed by k_pre b==0, IS[128..1248)): bases 128,288,448,608,768,928,1088.
// Per base B: subs B+s*16 (s<8, 112 blocks), root B+128, flag B+144. Max idx 1232 < 1248.
// Channel tables at IS[1280] (ws+5120). Signed atomicMax; 0xAA poison negative.

__device__ __forceinline__ void gbar(int* IS, int base, int bx) {
  // fence-free barrier (r3-proven): relaxed hierarchical arrive + relaxed system poll.
  // Caller: __syncthreads() before (drains all waves' vmem incl. agent stores) and after.
  asm volatile("s_waitcnt vmcnt(0)" ::: "memory");  // tid0's own RMWs complete before arrive
  int old = __hip_atomic_fetch_add(IS + base + (bx & 7) * 16, 1, __ATOMIC_RELAXED,
                                   __HIP_MEMORY_SCOPE_AGENT);
  if (old == 111) {
    int r = __hip_atomic_fetch_add(IS + base + 128, 1, __ATOMIC_RELAXED, __HIP_MEMORY_SCOPE_AGENT);
    if (r == 7)
      __hip_atomic_fetch_add(IS + base + 144, 1, __ATOMIC_RELAXED, __HIP_MEMORY_SCOPE_AGENT);
  }
  while (__hip_atomic_load(IS + base + 144, __ATOMIC_RELAXED, __HIP_MEMORY_SCOPE_SYSTEM) == 0)
    __builtin_amdgcn_s_sleep(2);
}

__device__ __forceinline__ void amax_body(const float4* __restrict__ p, int n4, int bid,
                                          int nblocks, int* __restrict__ slot) {
  const int tid = threadIdx.x;
  const int stride = nblocks * THREADS;
  float m = 0.0f;
  int i = bid * THREADS + tid;
  for (; i + 3 * stride < n4; i += 4 * stride) {
    float4 v0 = p[i];
    float4 v1 = p[i + stride];
    float4 v2 = p[i + 2 * stride];
    float4 v3 = p[i + 3 * stride];
    float m0 = fmaxf(fmaxf(fabsf(v0.x), fabsf(v0.y)), fmaxf(fabsf(v0.z), fabsf(v0.w)));
    float m1 = fmaxf(fmaxf(fabsf(v1.x), fabsf(v1.y)), fmaxf(fabsf(v1.z), fabsf(v1.w)));
    float m2 = fmaxf(fmaxf(fabsf(v2.x), fabsf(v2.y)), fmaxf(fabsf(v2.z), fabsf(v2.w)));
    float m3 = fmaxf(fmaxf(fabsf(v3.x), fabsf(v3.y)), fmaxf(fabsf(v3.z), fabsf(v3.w)));
    m = fmaxf(m, fmaxf(fmaxf(m0, m1), fmaxf(m2, m3)));
  }
  for (; i < n4; i += stride) {
    float4 v = p[i];
    m = fmaxf(m, fmaxf(fmaxf(fabsf(v.x), fabsf(v.y)), fmaxf(fabsf(v.z), fabsf(v.w))));
  }
#pragma unroll
  for (int k = 32; k >= 1; k >>= 1) m = fmaxf(m, __shfl_xor(m, k));
  __shared__ float wred[4];
  if ((tid & 63) == 0) wred[tid >> 6] = m;
  __syncthreads();
  if (tid == 0) {
    m = fmaxf(fmaxf(wred[0], wred[1]), fmaxf(wred[2], wred[3]));
    atomicMax(slot, __float_as_int(m));
  }
}

// Merged: blocks 0-2 bnfold(bn1,bn2,id); 3..66 w1 amax; 67..194 w2; 195..210 wid; 211..722 x.
// Block 0 also zeroes all grid-barrier counters (IS[128..1248)) for this launch/replay.
__global__ __launch_bounds__(THREADS) void k_pre(
    int* IS, const float* g1, const float* be1, const float* m1, const float* v1, float* wq1,
    float* b1, const float* g2, const float* be2, const float* m2, const float* v2, float* wq2,
    float* b2, const float* gi, const float* bei, const float* mi, const float* vvi, float* wqi,
    float* bi, const float4* w1, const float4* w2, const float4* wid, const float4* x) {
  int b = blockIdx.x;
  int c = threadIdx.x;
  if (b < 3) {
    if (b == 0) {
      IS[128 + c] = 0;
      IS[384 + c] = 0;
      IS[640 + c] = 0;
      IS[896 + c] = 0;
      if (c < 96) IS[1152 + c] = 0;
    }
    const float *gamma, *beta, *mean, *var;
    float *wq, *bb;
    if (b == 0) { gamma = g1; beta = be1; mean = m1; var = v1; wq = wq1; bb = b1; }
    else if (b == 1) { gamma = g2; beta = be2; mean = m2; var = v2; wq = wq2; bb = b2; }
    else { gamma = gi; beta = bei; mean = mi; var = vvi; wq = wqi; bb = bi; }
    __shared__ float red[THREADS];
    float ws = gamma[c] * (1.0f / sqrtf(var[c] + 1e-5f));
    red[c] = fabsf(ws);
    __syncthreads();
    for (int s = THREADS / 2; s > 0; s >>= 1) {
      if (c < s) red[c] = fmaxf(red[c], red[c + s]);
      __syncthreads();
    }
    float sws = fmaxf(red[0] / 127.0f, 1e-8f);
    float q = clamp8f(rintf(ws / sws)) * sws;
    wq[c] = q;
    bb[c] = beta[c] - mean[c] * q;
    return;
  }
  b -= 3;
  if (b < 64) { amax_body(w1, 73728, b, 64, IS + 1); return; }
  b -= 64;
  if (b < 128) { amax_body(w2, 147456, b, 128, IS + 2); return; }
  b -= 128;
  if (b < 16) { amax_body(wid, 8192, b, 16, IS + 3); return; }
  b -= 16;
  amax_body(x, 3211264, b, 512, IS + 0);
}

#define MFMA_I8(a, b, c) __builtin_amdgcn_mfma_i32_16x16x64_i8(a, b, c, 0, 0, 0)

// quant(h1) -> bn1 -> relu -> quant (scalar form, used in qh1 phase)
__device__ __forceinline__ signed char qact(int v, float sxw, float s_h1, float s_y2, float wq,
                                            float bb) {
  float hf = (float)v * sxw;
  float q = clamp8f(rintf(hf / s_h1));
  float hv = q * s_h1;
  float y = fmaxf(hv * wq + bb, 0.0f);
  float a = fminf(fmaxf(rintf(y / s_y2), -128.0f), 127.0f);
  return (signed char)(int)a;
}

__device__ __forceinline__ float sc_slot(const int* IS, int slot) {
  unsigned u = (unsigned)__hip_atomic_load((int*)(IS + slot), __ATOMIC_RELAXED,
                                           __HIP_MEMORY_SCOPE_AGENT);
  return fmaxf(__uint_as_float(u) / 127.0f, 1e-8f);
}

__device__ __forceinline__ void st_w16(vi4* dst, int r0, int r1, int r2, int r3) {
  // 16B weight store as 2x8B agent stores (cross-XCD visible pre-B0)
  unsigned long long lo = (unsigned long long)(unsigned)r0 |
                          ((unsigned long long)(unsigned)r1 << 32);
  unsigned long long hi = (unsigned long long)(unsigned)r2 |
                          ((unsigned long long)(unsigned)r3 << 32);
  unsigned long long* p = (unsigned long long*)dst;
  __hip_atomic_store(p, lo, __ATOMIC_RELAXED, __HIP_MEMORY_SCOPE_AGENT);
  __hip_atomic_store(p + 1, hi, __ATOMIC_RELAXED, __HIP_MEMORY_SCOPE_AGENT);
}

// ---- residual sum math ----
struct SumParams {
  float sxw2, s_h2, sxwid, s_idq;
};
__device__ __forceinline__ float sum_val(int v2, int vi, const SumParams& P, float wq2c, float b2c,
                                         float wqidc, float bidc) {
  float q2 = clamp8f(rintf((float)v2 * P.sxw2 / P.s_h2));
  float z = (q2 * P.s_h2) * wq2c + b2c;
  float qi = clamp8f(rintf((float)vi * P.sxwid / P.s_idq));
  float zi = (qi * P.s_idq) * wqidc + bidc;
  return z + zi;
}

// Fused quant + conv1 + conv2 stage (r12's k_ct + phase-0 quantize). Phase 0: weight quant
// ride-along (t<64, item g=bx*64+t) + qx (2 x-slices via LDS byte-tile transpose), outputs via
// agent stores -> gbar B0 -> plain-load consumers (r12's proven A2p lifecycle). Then conv1 +
// identity (accI in REGISTERS to the residual) + scales + qh1 -> A2 + conv2 + residual +
// requant + NCHW out. SEVEN fence-free barriers. H1/H2/IDI never touch HBM.
__global__ __launch_bounds__(THREADS, 4) void k_ct2(
    const float* __restrict__ x, const float* __restrict__ w1f, const float* __restrict__ w2f,
    const float* __restrict__ widf, int* X8, vi4* W1m, vi4* Widm, vi4* W2m, int* A2p, int* IS,
    const float* __restrict__ wq1, const float* __restrict__ b1, const float* __restrict__ wq2,
    const float* __restrict__ b2, const float* __restrict__ wqid, const float* __restrict__ bidp,
    float* __restrict__ out, int* maxS2, int* minS2) {
  __shared__ __align__(16) int lds[9280];  // phase0 byte-tile | stage1 5*58*32 | park h1 |
                                           // stage2 4*30*68 | sums [128][57] f32
  __shared__ int redA[4], redH[4];
  __shared__ int sVmax, sVmin;
  __shared__ float redF[4];
  __shared__ float sSxw, sSh1, sSy2, sSxwid, sSidq, sSxw2;
  __shared__ int sMh2;
  __shared__ float sOutS;
  const int tid = threadIdx.x;
  const int bx = blockIdx.x;
  const int n = bx / 28, rr = bx % 28;
  const int hp = rr >> 1, nh = rr & 1;
  const int ho0 = hp * 2;
  vi4 zero = {0, 0, 0, 0};
  const unsigned* ISu = (const unsigned*)IS;

  // ======== phase 0: quantize (scales from k_pre across kernel boundary) ========
  {
    // weight quant ride-along: one item per thread for t<64; 57344 = 896*64 exact
    if (tid < 64) {
      int g = bx * 64 + tid;
      if (g < 18432) {
        int tt = g;
        float s = sc_from_bits(ISu[1]);
        int lane2 = tt & 63;
        int cotile = (tt >> 6) & 15;
        int ks = tt >> 10;  // 0..17
        int tap = ks >> 1, kc = ks & 1;
        int kh = tap / 3, kw = tap % 3;
        int co = cotile * 16 + (lane2 & 15);
        int ci0 = kc * 64 + (lane2 >> 4) * 16;
        const float* src = w1f + (co * 128 + ci0) * 9 + kh * 3 + kw;
        int r[4];
#pragma unroll
        for (int q = 0; q < 4; ++q) {
          unsigned b0 = (unsigned char)q8(src[(q * 4 + 0) * 9], s);
          unsigned b1v = (unsigned char)q8(src[(q * 4 + 1) * 9], s);
          unsigned b2v = (unsigned char)q8(src[(q * 4 + 2) * 9], s);
          unsigned b3 = (unsigned char)q8(src[(q * 4 + 3) * 9], s);
          r[q] = (int)(b0 | (b1v << 8) | (b2v << 16) | (b3 << 24));
        }
        st_w16(&W1m[tt], r[0], r[1], r[2], r[3]);
      } else if (g < 55296) {
        int tt = g - 18432;  // < 36864
        float s = sc_from_bits(ISu[2]);
        int lane2 = tt & 63;
        int cotile = (tt >> 6) & 15;
        int ks = tt >> 10;  // 0..35
        int tap = ks >> 2, kc = ks & 3;
        int kh = tap / 3, kw = tap % 3;
        int co = cotile * 16 + (lane2 & 15);
        int ci0 = kc * 64 + (lane2 >> 4) * 16;
        const float* src = w2f + (co * 256 + ci0) * 9 + kh * 3 + kw;
        int r[4];
#pragma unroll
        for (int q = 0; q < 4; ++q) {
          unsigned b0 = (unsigned char)q8(src[(q * 4 + 0) * 9], s);
          unsigned b1v = (unsigned char)q8(src[(q * 4 + 1) * 9], s);
          unsigned b2v = (unsigned char)q8(src[(q * 4 + 2) * 9], s);
          unsigned b3 = (unsigned char)q8(src[(q * 4 + 3) * 9], s);
          r[q] = (int)(b0 | (b1v << 8) | (b2v << 16) | (b3 << 24));
        }
        st_w16(&W2m[tt], r[0], r[1], r[2], r[3]);
      } else {
        int tt = g - 55296;  // < 2048
        float s = sc_from_bits(ISu[3]);
        int lane2 = tt & 63;
        int cotile = (tt >> 6) & 15;
        int ks = tt >> 10;  // 0..1
        int co = cotile * 16 + (lane2 & 15);
        int ci0 = ks * 64 + (lane2 >> 4) * 16;
        const float* src = widf + co * 128 + ci0;
        int r[4];
#pragma unroll
        for (int q = 0; q < 4; ++q) {
          unsigned b0 = (unsigned char)q8(src[q * 4 + 0], s);
          unsigned b1v = (unsigned char)q8(src[q * 4 + 1], s);
          unsigned b2v = (unsigned char)q8(src[q * 4 + 2], s);
          unsigned b3 = (unsigned char)q8(src[q * 4 + 3], s);
          r[q] = (int)(b0 | (b1v << 8) | (b2v << 16) | (b3 << 24));
        }
        st_w16(&Widm[tt], r[0], r[1], r[2], r[3]);
      }
    }
    // qx: slices 2bx, 2bx+1 through the conflict-benign scalar LDS transpose
    signed char* tile = (signed char*)lds;  // 56*132 bytes
    const float sx = sc_from_bits(ISu[0]);
#pragma unroll 1
    for (int sl = 0; sl < 2; ++sl) {
      int s = bx * 2 + sl;
      int hq = s % 56, nq = s / 56;
      const float* xp = x + ((nq * 128) * 56 + hq) * 56;
#pragma unroll
      for (int k = 0; k < 28; ++k) {
        int i = tid + k * 256;  // < 7168
        tile[(i % 56) * 132 + (i / 56)] = q8(xp[(i / 56) * 3136 + (i % 56)], sx);
      }
      __syncthreads();
      int* op = X8 + (nq * 56 + hq) * 1792;
#pragma unroll
      for (int k = 0; k < 7; ++k) {
        int i = tid + k * 256;  // < 1792
        int w = i >> 5, c4 = (i & 31) * 4;
        const signed char* tp = tile + w * 132 + c4;
        __hip_atomic_store(op + i,
                           (int)(unsigned char)tp[0] | ((int)(unsigned char)tp[1] << 8) |
                               ((int)(unsigned char)tp[2] << 16) |
                               ((int)(unsigned char)tp[3] << 24),
                           __ATOMIC_RELAXED, __HIP_MEMORY_SCOPE_AGENT);
      }
      __syncthreads();  // pack reads done before tile overwrite / stage1 reuse
    }
  }
  if (tid == 0) gbar(IS, 128, bx);  // B0: X8 + quantized weights global
  __syncthreads();

  // ======== stage1: 5 input rows (plain vi4 loads; A2p-proven lifecycle), swizzled ========
  for (int r = 0; r < 5; ++r) {
    int h = 2 * ho0 - 1 + r;
    int* dst = lds + r * 58 * 32;
    if (h >= 0 && h < 56) {
      const vi4* src = (const vi4*)(X8 + (n * 56 + h) * 1792);
      for (int i4 = tid; i4 < 448; i4 += THREADS) {
        int col = i4 >> 3, e0 = (i4 & 7) * 4;
        int cell = r * 58 + col + 1;
        *(vi4*)(lds + cell * 32 + (e0 ^ ((cell & 7) << 2))) = src[i4];
      }
      if (tid < 32) dst[tid] = 0;
      else if (tid >= 128 && tid < 160) dst[57 * 32 + (tid - 128)] = 0;
    } else {
      for (int i4 = tid; i4 < 464; i4 += THREADS) ((vi4*)dst)[i4] = zero;
    }
  }
  __syncthreads();

  const int lane = tid & 63, wv = tid >> 6;
  const int mw = wv & 1, nw = wv >> 1;
  const int lm = lane & 15, quad = lane >> 4;
  const int woc0 = lm, woc1 = (16 + lm) > 27 ? 27 : (16 + lm);
  const int choff = quad * 4;
  const int ctbase = nh * 8 + nw * 4;

#define LDA(row, colp, sub)                                                              \
  (*(const vi4*)(lds + ((row) * 58 + (colp)) * 32 +                                      \
                 ((sub) ^ ((((row) * 58 + (colp)) & 7) << 2))))

  vi4 acc[2][4];
  vi4 accI[2][4];  // identity accumulator — LIVES IN REGISTERS until residual phase
  vi4 bA[4], bB[4];
  vi4 a0A, a1A, a0B, a1B;

  // ---- identity branch (2 K-steps) -> accI ----
#pragma unroll
  for (int mt = 0; mt < 2; ++mt)
#pragma unroll
    for (int ct = 0; ct < 4; ++ct) accI[mt][ct] = zero;
  const vi4* wibase = Widm + ctbase * 64 + lane;
  {
    const int row = 2 * mw + 1;
#pragma unroll
    for (int kc = 0; kc < 2; ++kc) {
      vi4 a0 = LDA(row, 2 * woc0 + 1, kc * 16 + choff);
      vi4 a1 = LDA(row, 2 * woc1 + 1, kc * 16 + choff);
#pragma unroll
      for (int ct = 0; ct < 4; ++ct) {
        vi4 b = wibase[kc * 1024 + ct * 64];
        accI[0][ct] = MFMA_I8(a0, b, accI[0][ct]);
        accI[1][ct] = MFMA_I8(a1, b, accI[1][ct]);
      }
    }
  }
  int am = 0;
#pragma unroll
  for (int ct = 0; ct < 4; ++ct)
#pragma unroll
    for (int mt = 0; mt < 2; ++mt)
#pragma unroll
      for (int r = 0; r < 4; ++r) {
        int wo = mt * 16 + quad * 4 + r;
        if (wo < 28) {
          int v = accI[mt][ct][r];
          am = max(am, v < 0 ? -v : v);
        }
      }
#pragma unroll
  for (int k = 32; k >= 1; k >>= 1) am = max(am, __shfl_xor(am, k));
  if (lane == 0) redA[wv] = am;

  // ---- main 3x3 conv1, 18 K-steps, ping-pong -> acc ----
#pragma unroll
  for (int mt = 0; mt < 2; ++mt)
#pragma unroll
    for (int ct = 0; ct < 4; ++ct) acc[mt][ct] = zero;
  const vi4* wbase = W1m + ctbase * 64 + lane;
#pragma unroll
  for (int ct = 0; ct < 4; ++ct) bA[ct] = wbase[ct * 64];
  {
    a0A = LDA(2 * mw, 2 * woc0, choff);
    a1A = LDA(2 * mw, 2 * woc1, choff);
  }
#pragma unroll 1
  for (int ks = 0; ks < 18; ks += 2) {
    {
      const int ksn = ks + 1;
      const int khn = (ksn >= 6) + (ksn >= 12);
      const int t2 = ksn - khn * 6;
      const int kwn = t2 >> 1, kcn = t2 & 1;
#pragma unroll
      for (int ct = 0; ct < 4; ++ct) bB[ct] = wbase[ksn * 1024 + ct * 64];
      const int row = 2 * mw + khn;
      a0B = LDA(row, 2 * woc0 + kwn, kcn * 16 + choff);
      a1B = LDA(row, 2 * woc1 + kwn, kcn * 16 + choff);
    }
#pragma unroll
    for (int ct = 0; ct < 4; ++ct) {
      acc[0][ct] = MFMA_I8(a0A, bA[ct], acc[0][ct]);
      acc[1][ct] = MFMA_I8(a1A, bA[ct], acc[1][ct]);
    }
    if (ks + 2 < 18) {
      const int ksn = ks + 2;
      const int khn = (ksn >= 6) + (ksn >= 12);
      const int t2 = ksn - khn * 6;
      const int kwn = t2 >> 1, kcn = t2 & 1;
#pragma unroll
      for (int ct = 0; ct < 4; ++ct) bA[ct] = wbase[ksn * 1024 + ct * 64];
      const int row = 2 * mw + khn;
      a0A = LDA(row, 2 * woc0 + kwn, kcn * 16 + choff);
      a1A = LDA(row, 2 * woc1 + kwn, kcn * 16 + choff);
    }
#pragma unroll
    for (int ct = 0; ct < 4; ++ct) {
      acc[0][ct] = MFMA_I8(a0B, bB[ct], acc[0][ct]);
      acc[1][ct] = MFMA_I8(a1B, bB[ct], acc[1][ct]);
    }
  }
#undef LDA

  // ---- per-channel extrema -> d_out scratch via AGENT stores ----
#pragma unroll
  for (int ct = 0; ct < 4; ++ct) {
    int vmax = INT_MIN, vmin = INT_MAX;
#pragma unroll
    for (int mt = 0; mt < 2; ++mt)
#pragma unroll
      for (int r = 0; r < 4; ++r) {
        int wo = mt * 16 + quad * 4 + r;
        if (wo < 28) {
          int v = acc[mt][ct][r];
          vmax = max(vmax, v);
          vmin = min(vmin, v);
        }
      }
    vmax = max(vmax, __shfl_xor(vmax, 16));
    vmax = max(vmax, __shfl_xor(vmax, 32));
    vmin = min(vmin, __shfl_xor(vmin, 16));
    vmin = min(vmin, __shfl_xor(vmin, 32));
    if (lane < 16) {
      int cl = (nw * 4 + ct) * 16 + lane;
      __hip_atomic_store(maxS2 + bx * 256 + mw * 128 + cl, vmax, __ATOMIC_RELAXED,
                         __HIP_MEMORY_SCOPE_AGENT);
      __hip_atomic_store(minS2 + bx * 256 + mw * 128 + cl, vmin, __ATOMIC_RELAXED,
                         __HIP_MEMORY_SCOPE_AGENT);
    }
  }

  __syncthreads();  // stage1 reads done; redA ready; all waves' stores drained
  if (tid == 0) {
    int a = max(max(redA[0], redA[1]), max(redA[2], redA[3]));
    atomicMax(IS + 5, a);  // id amax (device RMW)
  }
  // ---- park h1 into LDS [sp=mw*28+wo][130] (stage1 dead) ----
#pragma unroll
  for (int ct = 0; ct < 4; ++ct) {
    const int cl = (nw * 4 + ct) * 16 + lm;
#pragma unroll
    for (int mt = 0; mt < 2; ++mt)
#pragma unroll
      for (int r = 0; r < 4; ++r) {
        int wo = mt * 16 + quad * 4 + r;
        if (wo < 28) lds[(mw * 28 + wo) * 130 + cl] = acc[mt][ct][r];
      }
  }
  __syncthreads();
  if (tid == 0) gbar(IS, 288, bx);  // B1: extrema + IS[5] global
  __syncthreads();

  // ---- rs1a: 256 blocks reduce per-channel extrema ----
  if (bx < 256) {
    const int c = bx, nhc = c >> 7, cl = c & 127;
    int vmax = INT_MIN, vmin = INT_MAX;
    for (int j = tid; j < 896; j += THREADS) {
      int bxx = nhc + ((j >> 1) << 1);
      int mwj = j & 1;
      int a = __hip_atomic_load(maxS2 + bxx * 256 + mwj * 128 + cl, __ATOMIC_RELAXED,
                                __HIP_MEMORY_SCOPE_AGENT);
      int i_ = __hip_atomic_load(minS2 + bxx * 256 + mwj * 128 + cl, __ATOMIC_RELAXED,
                                 __HIP_MEMORY_SCOPE_AGENT);
      vmax = max(vmax, a);
      vmin = min(vmin, i_);
    }
    int* rMax = lds + 7280;
    int* rMin = lds + 7536;
    rMax[tid] = vmax;
    rMin[tid] = vmin;
    __syncthreads();
    for (int s = 128; s > 0; s >>= 1) {
      if (tid < s) {
        rMax[tid] = max(rMax[tid], rMax[tid + s]);
        rMin[tid] = min(rMin[tid], rMin[tid + s]);
      }
      __syncthreads();
    }
    if (tid == 0) {
      sVmax = rMax[0];
      sVmin = rMin[0];
      int a1 = sVmax < 0 ? -sVmax : sVmax;
      int a0 = sVmin < 0 ? -sVmin : sVmin;
      atomicMax(IS + 4, max(a1, a0));  // mh1
    }
  }
  __syncthreads();
  if (tid == 0) gbar(IS, 448, bx);  // B2: mh1 global
  __syncthreads();

  // ---- rs1b: per-channel rf -> IS[7] ----
  if (bx < 256 && tid == 0) {
    float sx = sc_slot(IS, 0);
    float sw1 = sc_slot(IS, 1);
    int mh1 = __hip_atomic_load(IS + 4, __ATOMIC_RELAXED, __HIP_MEMORY_SCOPE_AGENT);
    float sxw = sx * sw1;
    float s_h1 = fmaxf(sxw * (float)mh1 / 127.0f, 1e-8f);
    float wq = wq1[bx], bbc = b1[bx];
    float q1 = clamp8f(rintf((float)sVmax * sxw / s_h1));
    float q0 = clamp8f(rintf((float)sVmin * sxw / s_h1));
    float y1 = fmaxf(q1 * s_h1 * wq + bbc, 0.0f);
    float y0 = fmaxf(q0 * s_h1 * wq + bbc, 0.0f);
    atomicMax(IS + 7, __float_as_int(fmaxf(y1, y0)));  // rf >= 0
  }
  __syncthreads();
  if (tid == 0) gbar(IS, 608, bx);  // B3: rf global
  __syncthreads();

  // ---- scales, all local ----
  if (tid == 0) {
    float sx = sc_slot(IS, 0);
    float sw1 = sc_slot(IS, 1);
    int mh1 = __hip_atomic_load(IS + 4, __ATOMIC_RELAXED, __HIP_MEMORY_SCOPE_AGENT);
    int mrf = __hip_atomic_load(IS + 7, __ATOMIC_RELAXED, __HIP_MEMORY_SCOPE_AGENT);
    float sxw = sx * sw1;
    sSxw = sxw;
    sSh1 = fmaxf(sxw * (float)mh1 / 127.0f, 1e-8f);
    float s_y2 = fmaxf(__int_as_float(mrf) / 127.0f, 1e-8f);
    sSy2 = s_y2;
    int mid = __hip_atomic_load(IS + 5, __ATOMIC_RELAXED, __HIP_MEMORY_SCOPE_AGENT);
    float swid = sc_slot(IS, 3);
    sSxwid = sx * swid;
    sSidq = fmaxf(sx * swid * (float)mid / 127.0f, 1e-8f);
    sSxw2 = s_y2 * sc_slot(IS, 2);
  }
  __syncthreads();

  // ---- qh1 from parked LDS -> A2 via AGENT stores ----
  {
    const float sxw = sSxw, s_h1 = sSh1, s_y2 = sSy2;
#pragma unroll
    for (int k = 0; k < 7; ++k) {
      int i = tid + k * 256;  // < 1792
      int sp = i >> 5, c4i = i & 31;
      int mwp = sp >= 28 ? 1 : 0;
      int wo = sp - mwp * 28;
      int c0 = nh * 128 + c4i * 4;
      const int* pk = lds + sp * 130 + c4i * 4;
      unsigned r0 = (unsigned char)qact(pk[0], sxw, s_h1, s_y2, wq1[c0], b1[c0]);
      unsigned r1 = (unsigned char)qact(pk[1], sxw, s_h1, s_y2, wq1[c0 + 1], b1[c0 + 1]);
      unsigned r2 = (unsigned char)qact(pk[2], sxw, s_h1, s_y2, wq1[c0 + 2], b1[c0 + 2]);
      unsigned r3 = (unsigned char)qact(pk[3], sxw, s_h1, s_y2, wq1[c0 + 3], b1[c0 + 3]);
      __hip_atomic_store(A2p + ((n * 28 + ho0 + mwp) * 28 + wo) * 64 + nh * 32 + c4i,
                         (int)(r0 | (r1 << 8) | (r2 << 16) | (r3 << 24)), __ATOMIC_RELAXED,
                         __HIP_MEMORY_SCOPE_AGENT);
    }
  }
  __syncthreads();
  if (tid == 0) gbar(IS, 768, bx);  // B4: A2 global (halo rows)
  __syncthreads();

  // ---- stage2: A2 rows ho0-1..ho0+2 -> conv2 layout (plain vi4 loads) ----
  for (int r = 0; r < 4; ++r) {
    int h = ho0 - 1 + r;
    int* dst = lds + r * 30 * 68;
    if (h >= 0 && h < 28) {
      const vi4* src = (const vi4*)(A2p + (n * 28 + h) * 28 * 64);
      for (int i4 = tid; i4 < 448; i4 += THREADS) {
        int col = i4 >> 4, c = (i4 & 15) * 4;
        *(vi4*)(dst + (col + 1) * 68 + c) = src[i4];
      }
      if (tid < 64) dst[tid] = 0;
      else if (tid >= 128 && tid < 192) dst[29 * 68 + (tid - 128)] = 0;
    } else {
      for (int i4 = tid; i4 < 510; i4 += THREADS) ((vi4*)dst)[i4] = zero;
    }
  }
  __syncthreads();

  // ---- conv2 3x3 s1 p1, 36 K-steps, ping-pong -> acc ----
#pragma unroll
  for (int mt = 0; mt < 2; ++mt)
#pragma unroll
    for (int ct = 0; ct < 4; ++ct) acc[mt][ct] = zero;
  const vi4* wbase2 = W2m + ctbase * 64 + lane;
#pragma unroll
  for (int ct = 0; ct < 4; ++ct) bA[ct] = wbase2[ct * 64];
  {
    const int ro = mw * 30;  // ks=0
    a0A = *(const vi4*)(lds + (ro + woc0) * 68 + choff);
    a1A = *(const vi4*)(lds + (ro + woc1) * 68 + choff);
  }
#pragma unroll 1
  for (int ks = 0; ks < 36; ks += 2) {
    {
      const int ksn = ks + 1;
      const int khn = (ksn >= 12) + (ksn >= 24);
      const int t2 = ksn - khn * 12;
      const int kwn = t2 >> 2, kcn = t2 & 3;
#pragma unroll
      for (int ct = 0; ct < 4; ++ct) bB[ct] = wbase2[ksn * 1024 + ct * 64];
      const int ro = (mw + khn) * 30;
      a0B = *(const vi4*)(lds + (ro + woc0 + kwn) * 68 + kcn * 16 + choff);
      a1B = *(const vi4*)(lds + (ro + woc1 + kwn) * 68 + kcn * 16 + choff);
    }
#pragma unroll
    for (int ct = 0; ct < 4; ++ct) {
      acc[0][ct] = MFMA_I8(a0A, bA[ct], acc[0][ct]);
      acc[1][ct] = MFMA_I8(a1A, bA[ct], acc[1][ct]);
    }
    if (ks + 2 < 36) {
      const int ksn = ks + 2;
      const int khn = (ksn >= 12) + (ksn >= 24);
      const int t2 = ksn - khn * 12;
      const int kwn = t2 >> 2, kcn = t2 & 3;
#pragma unroll
      for (int ct = 0; ct < 4; ++ct) bA[ct] = wbase2[ksn * 1024 + ct * 64];
      const int ro = (mw + khn) * 30;
      a0A = *(const vi4*)(lds + (ro + woc0 + kwn) * 68 + kcn * 16 + choff);
      a1A = *(const vi4*)(lds + (ro + woc1 + kwn) * 68 + kcn * 16 + choff);
    }
#pragma unroll
    for (int ct = 0; ct < 4; ++ct) {
      acc[0][ct] = MFMA_I8(a0B, bB[ct], acc[0][ct]);
      acc[1][ct] = MFMA_I8(a1B, bB[ct], acc[1][ct]);
    }
  }

  // ---- block max|h2| straight from acc ----
  int am2 = 0;
#pragma unroll
  for (int ct = 0; ct < 4; ++ct)
#pragma unroll
    for (int mt = 0; mt < 2; ++mt)
#pragma unroll
      for (int r = 0; r < 4; ++r) {
        int wo = mt * 16 + quad * 4 + r;
        if (wo < 28) {
          int v = acc[mt][ct][r];
          am2 = max(am2, v < 0 ? -v : v);
        }
      }
#pragma unroll
  for (int k = 32; k >= 1; k >>= 1) am2 = max(am2, __shfl_xor(am2, k));
  if (lane == 0) redH[wv] = am2;
  __syncthreads();
  if (tid == 0) {
    atomicMax(IS + 6, max(max(redH[0], redH[1]), max(redH[2], redH[3])));
    gbar(IS, 928, bx);  // B5: max|h2| global
    sMh2 = __hip_atomic_load(IS + 6, __ATOMIC_RELAXED, __HIP_MEMORY_SCOPE_SYSTEM);
  }
  __syncthreads();

  SumParams P;
  P.sxw2 = sSxw2;
  P.s_h2 = fmaxf(sSxw2 * (float)sMh2 / 127.0f, 1e-8f);
  P.sxwid = sSxwid;
  P.s_idq = sSidq;

  // ---- residual: identity STRAIGHT FROM accI registers ----
  float* sums = (float*)lds;  // [128][57] f32, overwrites conv2 staging (dead)
  float fm = 0.0f;
#pragma unroll
  for (int ct = 0; ct < 4; ++ct) {
    const int co = (ctbase + ct) * 16 + lm;
    const int cl = co - nh * 128;
    float w2c = wq2[co], b2c = b2[co], wic = wqid[co], bic = bidp[co];
#pragma unroll
    for (int mt = 0; mt < 2; ++mt)
#pragma unroll
      for (int r = 0; r < 4; ++r) {
        int wo = mt * 16 + quad * 4 + r;
        if (wo < 28) {
          int slot = cl * 57 + mw * 28 + wo;
          float sv = sum_val(acc[mt][ct][r], accI[mt][ct][r], P, w2c, b2c, wic, bic);
          sums[slot] = sv;
          fm = fmaxf(fm, fabsf(sv));
        }
      }
  }
#pragma unroll
  for (int k = 32; k >= 1; k >>= 1) fm = fmaxf(fm, __shfl_xor(fm, k));
  if (lane == 0) redF[wv] = fm;
  __syncthreads();
  if (tid == 0) {
    float a = fmaxf(fmaxf(redF[0], redF[1]), fmaxf(redF[2], redF[3]));
    atomicMax(IS + 11, __float_as_int(a));
    gbar(IS, 1088, bx);  // B6: max|sum| global
    int mb = __hip_atomic_load(IS + 11, __ATOMIC_RELAXED, __HIP_MEMORY_SCOPE_SYSTEM);
    sOutS = fmaxf(__int_as_float(mb) / 127.0f, 1e-8f);
  }
  __syncthreads();
  const float out_s = sOutS;

  // ---- requant + relu, NCHW write ----
  float* ob = out + n * 200704 + (nh * 128) * 784 + ho0 * 28;
#pragma unroll
  for (int k = 0; k < 28; ++k) {
    int idx = tid + k * 256;
    int cl = idx / 56, rem = idx % 56;
    float sv = sums[cl * 57 + rem];
    float q = clamp8f(rintf(sv / out_s));
    ob[cl * 784 + rem] = q > 0.0f ? q * out_s : 0.0f;
  }
  if (bx == 0 && tid == 0) out[6422528] = out_s;
}

extern "C" void kernel_launch(void* const* d_in, const int* in_sizes, int n_in, void* d_out,
                              int out_size, void* d_ws, size_t ws_size, hipStream_t stream) {
  (void)in_sizes; (void)n_in; (void)out_size; (void)ws_size;
  const float* x = (const float*)d_in[0];
  const float* w1 = (const float*)d_in[1];
  const float* w2 = (const float*)d_in[2];
  const float* wid = (const float*)d_in[3];
  const float* bn1g = (const float*)d_in[4];
  const float* bn1b = (const float*)d_in[5];
  const float* bn1m = (const float*)d_in[6];
  const float* bn1v = (const float*)d_in[7];
  const float* bn2g = (const float*)d_in[8];
  const float* bn2b = (const float*)d_in[9];
  const float* bn2m = (const float*)d_in[10];
  const float* bn2v = (const float*)d_in[11];
  const float* idg = (const float*)d_in[12];
  const float* idb = (const float*)d_in[13];
  const float* idm = (const float*)d_in[14];
  const float* idv = (const float*)d_in[15];

  char* ws = (char*)d_ws;
  int* IS = (int*)ws;
  // barrier counters occupy IS[128..1248); per-channel tables at ws+5120:
  float* wq1 = (float*)(ws + 5120);
  float* b1 = (float*)(ws + 6144);
  float* wq2 = (float*)(ws + 7168);
  float* b2 = (float*)(ws + 8192);
  float* wqid = (float*)(ws + 9216);
  float* bid = (float*)(ws + 10240);
  char* X8 = ws + 16384;  // NHWC int8 (agent-stored in k_ct2 phase 0, plain-read post-B0)
  char* W1m = X8 + 12845056;
  char* W2m = W1m + 294912;
  char* Widm = W2m + 589824;
  int* A2p = (int*)(Widm + 32768);  // A2 int8 as ints
  float* out = (float*)d_out;
  int* maxS2 = (int*)d_out;  // extrema scratch in d_out (dead until k_ct2's final out write)
  int* minS2 = maxS2 + 896 * 256;

  k_pre<<<723, THREADS, 0, stream>>>(IS, bn1g, bn1b, bn1m, bn1v, wq1, b1, bn2g, bn2b, bn2m, bn2v,
                                     wq2, b2, idg, idb, idm, idv, wqid, bid, (const float4*)w1,
                                     (const float4*)w2, (const float4*)wid, (const float4*)x);
  k_ct2<<<GRID_BLOCKS, THREADS, 0, stream>>>(x, w1, w2, wid, (int*)X8, (vi4*)W1m, (vi4*)Widm,
                                             (vi4*)W2m, A2p, IS, wq1, b1, wq2, b2, wqid, bid, out,
                                             maxS2, minS2);
}

// Round 14
// 238.220 us; speedup vs baseline: 1.1323x; 1.1323x over previous
//
#include <hip/hip_runtime.h>
#include <limits.h>

#define THREADS 256
#define GRID_BLOCKS 896

typedef int vi4 __attribute__((ext_vector_type(4)));

__device__ __forceinline__ float clamp8f(float q) { return fminf(fmaxf(q, -128.0f), 127.0f); }
__device__ __forceinline__ float sc_from_bits(unsigned b) {
  return fmaxf(__uint_as_float(b) / 127.0f, 1e-8f);
}
__device__ __forceinline__ signed char q8(float v, float s) {
  return (signed char)(int)clamp8f(rintf(v / s));
}

// ===== r14 FINAL: r12 configuration (session best, 239.2us; entry baseline 252.6us). =====
// Session ledger (causal, each item bench-verified):
//  r1: hipLaunchCooperativeKernel is not graph-capturable -> silent no-op. Software barrier.
//  r2: acquire-per-poll spin = per-iteration L2 cache maintenance storm (k_tail 310us).
//  r3: FENCE-FREE hierarchical barrier (relaxed arrive + relaxed system poll; data via
//      device-scope RMW; s_waitcnt vmcnt(0) before arrive) -> k_tail 67us. Foundation.
//  r4: conv1+scales+qh1 fused w/ 3 barriers + d_out extrema scratch -> 246.9 (repro 249.8 r11).
//  r5: 2016-block barrier front forces (256,8)=64 VGPR -> load pipelining dies (+26us).
//  r6/r8/r9 deconfound: qx-float4 LDS byte-merge exonerated; hipMemsetAsync exonerated;
//      cv1-r5 (2-barrier, extrema-in-VGPR) was the +12us despite less nominal work.
//  r7: xs[56] register-parked x spills at (256,4); k_tail dur is modulated by front skew.
//  r10: transient node core-dump (reproduced clean r11).
//  r12: conv1+conv2 merged (k_ct): identity residual FROM REGISTERS, IDI/H1/H2 never HBM,
//       6 barriers, VGPR 64 -> 239.2 BEST.
//  r13: absorbing quantize via megabyte-scale agent-scope stores = ~3x write amplification
//       (WRITE 124MB vs 44MB) -> 269.7. UC stores only for small scratch; streaming data
//       crosses kernel boundaries.
// Scalar slots: [0] amax_x [1] amax_w1 [2] amax_w2 [3] amax_wid
// [4] maxabs_h1 [5] maxabs_id [6] maxabs_h2 [7] max_y2(rf) [11] amax_sum
// Grid barriers (zeroed by k_pre b==0, IS[128..1088)): bases 128,288,448,608,768,928.
// Per base B: subs B+s*16 (s<8, 112 blocks), root B+128, flag B+144. Max idx 1072 < 1152.
// Channel tables start at IS[1152] (ws+4608). Signed atomicMax; 0xAA poison negative.

__device__ __forceinline__ void gbar(int* IS, int base, int bx) {
  // fence-free barrier (r3-proven): relaxed hierarchical arrive + relaxed system poll.
  // Caller: __syncthreads() before (drains all waves' vmem incl. agent stores) and after.
  asm volatile("s_waitcnt vmcnt(0)" ::: "memory");  // tid0's own RMWs complete before arrive
  int old = __hip_atomic_fetch_add(IS + base + (bx & 7) * 16, 1, __ATOMIC_RELAXED,
                                   __HIP_MEMORY_SCOPE_AGENT);
  if (old == 111) {
    int r = __hip_atomic_fetch_add(IS + base + 128, 1, __ATOMIC_RELAXED, __HIP_MEMORY_SCOPE_AGENT);
    if (r == 7)
      __hip_atomic_fetch_add(IS + base + 144, 1, __ATOMIC_RELAXED, __HIP_MEMORY_SCOPE_AGENT);
  }
  while (__hip_atomic_load(IS + base + 144, __ATOMIC_RELAXED, __HIP_MEMORY_SCOPE_SYSTEM) == 0)
    __builtin_amdgcn_s_sleep(2);
}

__device__ __forceinline__ void amax_body(const float4* __restrict__ p, int n4, int bid,
                                          int nblocks, int* __restrict__ slot) {
  const int tid = threadIdx.x;
  const int stride = nblocks * THREADS;
  float m = 0.0f;
  int i = bid * THREADS + tid;
  for (; i + 3 * stride < n4; i += 4 * stride) {
    float4 v0 = p[i];
    float4 v1 = p[i + stride];
    float4 v2 = p[i + 2 * stride];
    float4 v3 = p[i + 3 * stride];
    float m0 = fmaxf(fmaxf(fabsf(v0.x), fabsf(v0.y)), fmaxf(fabsf(v0.z), fabsf(v0.w)));
    float m1 = fmaxf(fmaxf(fabsf(v1.x), fabsf(v1.y)), fmaxf(fabsf(v1.z), fabsf(v1.w)));
    float m2 = fmaxf(fmaxf(fabsf(v2.x), fabsf(v2.y)), fmaxf(fabsf(v2.z), fabsf(v2.w)));
    float m3 = fmaxf(fmaxf(fabsf(v3.x), fabsf(v3.y)), fmaxf(fabsf(v3.z), fabsf(v3.w)));
    m = fmaxf(m, fmaxf(fmaxf(m0, m1), fmaxf(m2, m3)));
  }
  for (; i < n4; i += stride) {
    float4 v = p[i];
    m = fmaxf(m, fmaxf(fmaxf(fabsf(v.x), fabsf(v.y)), fmaxf(fabsf(v.z), fabsf(v.w))));
  }
#pragma unroll
  for (int k = 32; k >= 1; k >>= 1) m = fmaxf(m, __shfl_xor(m, k));
  __shared__ float wred[4];
  if ((tid & 63) == 0) wred[tid >> 6] = m;
  __syncthreads();
  if (tid == 0) {
    m = fmaxf(fmaxf(wred[0], wred[1]), fmaxf(wred[2], wred[3]));
    atomicMax(slot, __float_as_int(m));
  }
}

// Merged: blocks 0-2 bnfold(bn1,bn2,id); 3..66 w1 amax; 67..194 w2; 195..210 wid; 211..722 x.
// Block 0 also zeroes all grid-barrier counters (IS[128..1088)) for this launch/replay.
__global__ __launch_bounds__(THREADS) void k_pre(
    int* IS, const float* g1, const float* be1, const float* m1, const float* v1, float* wq1,
    float* b1, const float* g2, const float* be2, const float* m2, const float* v2, float* wq2,
    float* b2, const float* gi, const float* bei, const float* mi, const float* vvi, float* wqi,
    float* bi, const float4* w1, const float4* w2, const float4* wid, const float4* x) {
  int b = blockIdx.x;
  int c = threadIdx.x;
  if (b < 3) {
    if (b == 0) {
      IS[128 + c] = 0;
      IS[384 + c] = 0;
      IS[640 + c] = 0;
      if (c < 192) IS[896 + c] = 0;
    }
    const float *gamma, *beta, *mean, *var;
    float *wq, *bb;
    if (b == 0) { gamma = g1; beta = be1; mean = m1; var = v1; wq = wq1; bb = b1; }
    else if (b == 1) { gamma = g2; beta = be2; mean = m2; var = v2; wq = wq2; bb = b2; }
    else { gamma = gi; beta = bei; mean = mi; var = vvi; wq = wqi; bb = bi; }
    __shared__ float red[THREADS];
    float ws = gamma[c] * (1.0f / sqrtf(var[c] + 1e-5f));
    red[c] = fabsf(ws);
    __syncthreads();
    for (int s = THREADS / 2; s > 0; s >>= 1) {
      if (c < s) red[c] = fmaxf(red[c], red[c + s]);
      __syncthreads();
    }
    float sws = fmaxf(red[0] / 127.0f, 1e-8f);
    float q = clamp8f(rintf(ws / sws)) * sws;
    wq[c] = q;
    bb[c] = beta[c] - mean[c] * q;
    return;
  }
  b -= 3;
  if (b < 64) { amax_body(w1, 73728, b, 64, IS + 1); return; }
  b -= 64;
  if (b < 128) { amax_body(w2, 147456, b, 128, IS + 2); return; }
  b -= 128;
  if (b < 16) { amax_body(wid, 8192, b, 16, IS + 3); return; }
  b -= 16;
  amax_body(x, 3211264, b, 512, IS + 0);
}

// Merged quantize: blocks [0,1792) qx; [1792,1864) qw1; [1864,2008) qw2; [2008,2016) qwid.
__global__ __launch_bounds__(THREADS) void k_quant(const float* __restrict__ x,
                                                   int* __restrict__ X8,
                                                   const float* __restrict__ w1f,
                                                   vi4* __restrict__ W1m,
                                                   const float* __restrict__ w2f,
                                                   vi4* __restrict__ W2m,
                                                   const float* __restrict__ widf,
                                                   vi4* __restrict__ Widm,
                                                   const unsigned* __restrict__ ISu) {
  __shared__ signed char tile[56 * 132];
  int b = blockIdx.x;
  int t = threadIdx.x;
  if (b < 1792) {
    float s = sc_from_bits(ISu[0]);
    int h = b % 56, n = b / 56;
    const float* xp = x + ((n * 128) * 56 + h) * 56;
#pragma unroll
    for (int k = 0; k < 28; ++k) {
      int i = t + k * 256;  // < 7168
      int w = i % 56, c = i / 56;
      tile[w * 132 + c] = q8(xp[c * 3136 + w], s);
    }
    __syncthreads();
    int* op = X8 + (n * 56 + h) * 56 * 32;
#pragma unroll
    for (int k = 0; k < 7; ++k) {
      int i = t + k * 256;  // < 1792
      int w = i >> 5, c4 = (i & 31) * 4;
      const signed char* tp = tile + w * 132 + c4;
      op[i] = (int)(unsigned char)tp[0] | ((int)(unsigned char)tp[1] << 8) |
              ((int)(unsigned char)tp[2] << 16) | ((int)(unsigned char)tp[3] << 24);
    }
    return;
  }
  if (b < 1864) {
    int tt = (b - 1792) * THREADS + t;  // < 18432
    float s = sc_from_bits(ISu[1]);
    int lane = tt & 63;
    int cotile = (tt >> 6) & 15;
    int ks = tt >> 10;  // 0..17
    int tap = ks >> 1, kc = ks & 1;
    int kh = tap / 3, kw = tap % 3;
    int co = cotile * 16 + (lane & 15);
    int ci0 = kc * 64 + (lane >> 4) * 16;
    const float* src = w1f + (co * 128 + ci0) * 9 + kh * 3 + kw;
    int r[4];
#pragma unroll
    for (int q = 0; q < 4; ++q) {
      unsigned b0 = (unsigned char)q8(src[(q * 4 + 0) * 9], s);
      unsigned b1 = (unsigned char)q8(src[(q * 4 + 1) * 9], s);
      unsigned b2 = (unsigned char)q8(src[(q * 4 + 2) * 9], s);
      unsigned b3 = (unsigned char)q8(src[(q * 4 + 3) * 9], s);
      r[q] = (int)(b0 | (b1 << 8) | (b2 << 16) | (b3 << 24));
    }
    vi4 v = {r[0], r[1], r[2], r[3]};
    W1m[tt] = v;
    return;
  }
  if (b < 2008) {
    int tt = (b - 1864) * THREADS + t;  // < 36864
    float s = sc_from_bits(ISu[2]);
    int lane = tt & 63;
    int cotile = (tt >> 6) & 15;
    int ks = tt >> 10;  // 0..35
    int tap = ks >> 2, kc = ks & 3;
    int kh = tap / 3, kw = tap % 3;
    int co = cotile * 16 + (lane & 15);
    int ci0 = kc * 64 + (lane >> 4) * 16;
    const float* src = w2f + (co * 256 + ci0) * 9 + kh * 3 + kw;
    int r[4];
#pragma unroll
    for (int q = 0; q < 4; ++q) {
      unsigned b0 = (unsigned char)q8(src[(q * 4 + 0) * 9], s);
      unsigned b1 = (unsigned char)q8(src[(q * 4 + 1) * 9], s);
      unsigned b2 = (unsigned char)q8(src[(q * 4 + 2) * 9], s);
      unsigned b3 = (unsigned char)q8(src[(q * 4 + 3) * 9], s);
      r[q] = (int)(b0 | (b1 << 8) | (b2 << 16) | (b3 << 24));
    }
    vi4 v = {r[0], r[1], r[2], r[3]};
    W2m[tt] = v;
    return;
  }
  {
    int tt = (b - 2008) * THREADS + t;  // < 2048
    float s = sc_from_bits(ISu[3]);
    int lane = tt & 63;
    int cotile = (tt >> 6) & 15;
    int ks = tt >> 10;  // 0..1
    int co = cotile * 16 + (lane & 15);
    int ci0 = ks * 64 + (lane >> 4) * 16;
    const float* src = widf + co * 128 + ci0;
    int r[4];
#pragma unroll
    for (int q = 0; q < 4; ++q) {
      unsigned b0 = (unsigned char)q8(src[q * 4 + 0], s);
      unsigned b1 = (unsigned char)q8(src[q * 4 + 1], s);
      unsigned b2 = (unsigned char)q8(src[q * 4 + 2], s);
      unsigned b3 = (unsigned char)q8(src[q * 4 + 3], s);
      r[q] = (int)(b0 | (b1 << 8) | (b2 << 16) | (b3 << 24));
    }
    vi4 v = {r[0], r[1], r[2], r[3]};
    Widm[tt] = v;
  }
}

#define MFMA_I8(a, b, c) __builtin_amdgcn_mfma_i32_16x16x64_i8(a, b, c, 0, 0, 0)

// quant(h1) -> bn1 -> relu -> quant (scalar form, used in qh1 phase)
__device__ __forceinline__ signed char qact(int v, float sxw, float s_h1, float s_y2, float wq,
                                            float bb) {
  float hf = (float)v * sxw;
  float q = clamp8f(rintf(hf / s_h1));
  float hv = q * s_h1;
  float y = fmaxf(hv * wq + bb, 0.0f);
  float a = fminf(fmaxf(rintf(y / s_y2), -128.0f), 127.0f);
  return (signed char)(int)a;
}

__device__ __forceinline__ float sc_slot(const int* IS, int slot) {
  unsigned u = (unsigned)__hip_atomic_load((int*)(IS + slot), __ATOMIC_RELAXED,
                                           __HIP_MEMORY_SCOPE_AGENT);
  return fmaxf(__uint_as_float(u) / 127.0f, 1e-8f);
}

// ---- residual sum math ----
struct SumParams {
  float sxw2, s_h2, sxwid, s_idq;
};
__device__ __forceinline__ float sum_val(int v2, int vi, const SumParams& P, float wq2c, float b2c,
                                         float wqidc, float bidc) {
  float q2 = clamp8f(rintf((float)v2 * P.sxw2 / P.s_h2));
  float z = (q2 * P.s_h2) * wq2c + b2c;
  float qi = clamp8f(rintf((float)vi * P.sxwid / P.s_idq));
  float zi = (qi * P.s_idq) * wqidc + bidc;
  return z + zi;
}

// Fused conv1+conv2 stage: conv1 3x3 s2 p1 + identity 1x1 s2 (acc kept in REGISTERS through
// the whole kernel) + grid scale derivation + qh1 -> A2 (agent stores, fresh region) + conv2
// 3x3 s1 p1 + residual (identity from registers!) + requant + NCHW out. SIX fence-free
// barriers (128,288,448,608,768,928). H1, H2, IDI never touch HBM.
// (256,4): LDS 37.1KB -> 1024 slots >= 896 co-resident by construction.
__global__ __launch_bounds__(THREADS, 4) void k_ct(
    const int* X8, const vi4* __restrict__ W1m, const vi4* __restrict__ Widm,
    const vi4* __restrict__ W2m, int* A2p, int* IS, const float* __restrict__ wq1,
    const float* __restrict__ b1, const float* __restrict__ wq2, const float* __restrict__ b2,
    const float* __restrict__ wqid, const float* __restrict__ bidp, float* __restrict__ out,
    int* maxS2, int* minS2) {
  __shared__ __align__(16) int lds[9280];  // stage1 5*58*32 | park h1 [56][130]+reduce |
                                           // stage2 4*30*68 | sums [128][57] f32
  __shared__ int redA[4], redH[4];
  __shared__ int sVmax, sVmin;
  __shared__ float redF[4];
  __shared__ float sSxw, sSh1, sSy2, sSxwid, sSidq, sSxw2;
  __shared__ int sMh2;
  __shared__ float sOutS;
  const int tid = threadIdx.x;
  const int bx = blockIdx.x;
  const int n = bx / 28, rr = bx % 28;
  const int hp = rr >> 1, nh = rr & 1;
  const int ho0 = hp * 2;
  vi4 zero = {0, 0, 0, 0};

  // ---- stage1: 5 input rows, swizzled stride-32 ----
  for (int r = 0; r < 5; ++r) {
    int h = 2 * ho0 - 1 + r;
    int* dst = lds + r * 58 * 32;
    if (h >= 0 && h < 56) {
      const vi4* src = (const vi4*)(X8 + (n * 56 + h) * 56 * 32);
      for (int i4 = tid; i4 < 448; i4 += THREADS) {
        int col = i4 >> 3, e0 = (i4 & 7) * 4;
        int cell = r * 58 + col + 1;
        *(vi4*)(lds + cell * 32 + (e0 ^ ((cell & 7) << 2))) = src[i4];
      }
      if (tid < 32) dst[tid] = 0;
      else if (tid >= 128 && tid < 160) dst[57 * 32 + (tid - 128)] = 0;
    } else {
      for (int i4 = tid; i4 < 464; i4 += THREADS) ((vi4*)dst)[i4] = zero;
    }
  }
  __syncthreads();

  const int lane = tid & 63, wv = tid >> 6;
  const int mw = wv & 1, nw = wv >> 1;
  const int lm = lane & 15, quad = lane >> 4;
  const int woc0 = lm, woc1 = (16 + lm) > 27 ? 27 : (16 + lm);
  const int choff = quad * 4;
  const int ctbase = nh * 8 + nw * 4;

#define LDA(row, colp, sub)                                                              \
  (*(const vi4*)(lds + ((row) * 58 + (colp)) * 32 +                                      \
                 ((sub) ^ ((((row) * 58 + (colp)) & 7) << 2))))

  vi4 acc[2][4];
  vi4 accI[2][4];  // identity branch accumulator — LIVES IN REGISTERS until residual phase
  vi4 bA[4], bB[4];
  vi4 a0A, a1A, a0B, a1B;

  // ---- identity branch (2 K-steps) -> accI ----
#pragma unroll
  for (int mt = 0; mt < 2; ++mt)
#pragma unroll
    for (int ct = 0; ct < 4; ++ct) accI[mt][ct] = zero;
  const vi4* wibase = Widm + ctbase * 64 + lane;
  {
    const int row = 2 * mw + 1;
#pragma unroll
    for (int kc = 0; kc < 2; ++kc) {
      vi4 a0 = LDA(row, 2 * woc0 + 1, kc * 16 + choff);
      vi4 a1 = LDA(row, 2 * woc1 + 1, kc * 16 + choff);
#pragma unroll
      for (int ct = 0; ct < 4; ++ct) {
        vi4 b = wibase[kc * 1024 + ct * 64];
        accI[0][ct] = MFMA_I8(a0, b, accI[0][ct]);
        accI[1][ct] = MFMA_I8(a1, b, accI[1][ct]);
      }
    }
  }
  int am = 0;
#pragma unroll
  for (int ct = 0; ct < 4; ++ct)
#pragma unroll
    for (int mt = 0; mt < 2; ++mt)
#pragma unroll
      for (int r = 0; r < 4; ++r) {
        int wo = mt * 16 + quad * 4 + r;
        if (wo < 28) {
          int v = accI[mt][ct][r];
          am = max(am, v < 0 ? -v : v);
        }
      }
#pragma unroll
  for (int k = 32; k >= 1; k >>= 1) am = max(am, __shfl_xor(am, k));
  if (lane == 0) redA[wv] = am;

  // ---- main 3x3 conv1, 18 K-steps, ping-pong -> acc ----
#pragma unroll
  for (int mt = 0; mt < 2; ++mt)
#pragma unroll
    for (int ct = 0; ct < 4; ++ct) acc[mt][ct] = zero;
  const vi4* wbase = W1m + ctbase * 64 + lane;
#pragma unroll
  for (int ct = 0; ct < 4; ++ct) bA[ct] = wbase[ct * 64];
  {
    a0A = LDA(2 * mw, 2 * woc0, choff);
    a1A = LDA(2 * mw, 2 * woc1, choff);
  }
#pragma unroll 1
  for (int ks = 0; ks < 18; ks += 2) {
    {
      const int ksn = ks + 1;
      const int khn = (ksn >= 6) + (ksn >= 12);
      const int t2 = ksn - khn * 6;
      const int kwn = t2 >> 1, kcn = t2 & 1;
#pragma unroll
      for (int ct = 0; ct < 4; ++ct) bB[ct] = wbase[ksn * 1024 + ct * 64];
      const int row = 2 * mw + khn;
      a0B = LDA(row, 2 * woc0 + kwn, kcn * 16 + choff);
      a1B = LDA(row, 2 * woc1 + kwn, kcn * 16 + choff);
    }
#pragma unroll
    for (int ct = 0; ct < 4; ++ct) {
      acc[0][ct] = MFMA_I8(a0A, bA[ct], acc[0][ct]);
      acc[1][ct] = MFMA_I8(a1A, bA[ct], acc[1][ct]);
    }
    if (ks + 2 < 18) {
      const int ksn = ks + 2;
      const int khn = (ksn >= 6) + (ksn >= 12);
      const int t2 = ksn - khn * 6;
      const int kwn = t2 >> 1, kcn = t2 & 1;
#pragma unroll
      for (int ct = 0; ct < 4; ++ct) bA[ct] = wbase[ksn * 1024 + ct * 64];
      const int row = 2 * mw + khn;
      a0A = LDA(row, 2 * woc0 + kwn, kcn * 16 + choff);
      a1A = LDA(row, 2 * woc1 + kwn, kcn * 16 + choff);
    }
#pragma unroll
    for (int ct = 0; ct < 4; ++ct) {
      acc[0][ct] = MFMA_I8(a0B, bB[ct], acc[0][ct]);
      acc[1][ct] = MFMA_I8(a1B, bB[ct], acc[1][ct]);
    }
  }
#undef LDA

  // ---- per-channel extrema -> d_out scratch via AGENT stores (cross-XCD visible) ----
#pragma unroll
  for (int ct = 0; ct < 4; ++ct) {
    int vmax = INT_MIN, vmin = INT_MAX;
#pragma unroll
    for (int mt = 0; mt < 2; ++mt)
#pragma unroll
      for (int r = 0; r < 4; ++r) {
        int wo = mt * 16 + quad * 4 + r;
        if (wo < 28) {
          int v = acc[mt][ct][r];
          vmax = max(vmax, v);
          vmin = min(vmin, v);
        }
      }
    vmax = max(vmax, __shfl_xor(vmax, 16));
    vmax = max(vmax, __shfl_xor(vmax, 32));
    vmin = min(vmin, __shfl_xor(vmin, 16));
    vmin = min(vmin, __shfl_xor(vmin, 32));
    if (lane < 16) {
      int cl = (nw * 4 + ct) * 16 + lane;
      __hip_atomic_store(maxS2 + bx * 256 + mw * 128 + cl, vmax, __ATOMIC_RELAXED,
                         __HIP_MEMORY_SCOPE_AGENT);
      __hip_atomic_store(minS2 + bx * 256 + mw * 128 + cl, vmin, __ATOMIC_RELAXED,
                         __HIP_MEMORY_SCOPE_AGENT);
    }
  }

  __syncthreads();  // stage1 reads done; redA ready; all waves' stores drained
  if (tid == 0) {
    int a = max(max(redA[0], redA[1]), max(redA[2], redA[3]));
    atomicMax(IS + 5, a);  // id amax (device RMW)
  }
  // ---- park h1 into LDS [sp=mw*28+wo][130] (stage1 dead) ----
#pragma unroll
  for (int ct = 0; ct < 4; ++ct) {
    const int cl = (nw * 4 + ct) * 16 + lm;
#pragma unroll
    for (int mt = 0; mt < 2; ++mt)
#pragma unroll
      for (int r = 0; r < 4; ++r) {
        int wo = mt * 16 + quad * 4 + r;
        if (wo < 28) lds[(mw * 28 + wo) * 130 + cl] = acc[mt][ct][r];
      }
  }
  __syncthreads();
  if (tid == 0) gbar(IS, 128, bx);  // B1: extrema + IS[5] global
  __syncthreads();

  // ---- rs1a: 256 blocks reduce per-channel extrema ----
  if (bx < 256) {
    const int c = bx, nhc = c >> 7, cl = c & 127;
    int vmax = INT_MIN, vmin = INT_MAX;
    for (int j = tid; j < 896; j += THREADS) {
      int bxx = nhc + ((j >> 1) << 1);
      int mwj = j & 1;
      int a = __hip_atomic_load(maxS2 + bxx * 256 + mwj * 128 + cl, __ATOMIC_RELAXED,
                                __HIP_MEMORY_SCOPE_AGENT);
      int i_ = __hip_atomic_load(minS2 + bxx * 256 + mwj * 128 + cl, __ATOMIC_RELAXED,
                                 __HIP_MEMORY_SCOPE_AGENT);
      vmax = max(vmax, a);
      vmin = min(vmin, i_);
    }
    int* rMax = lds + 7280;
    int* rMin = lds + 7536;
    rMax[tid] = vmax;
    rMin[tid] = vmin;
    __syncthreads();
    for (int s = 128; s > 0; s >>= 1) {
      if (tid < s) {
        rMax[tid] = max(rMax[tid], rMax[tid + s]);
        rMin[tid] = min(rMin[tid], rMin[tid + s]);
      }
      __syncthreads();
    }
    if (tid == 0) {
      sVmax = rMax[0];
      sVmin = rMin[0];
      int a1 = sVmax < 0 ? -sVmax : sVmax;
      int a0 = sVmin < 0 ? -sVmin : sVmin;
      atomicMax(IS + 4, max(a1, a0));  // mh1
    }
  }
  __syncthreads();
  if (tid == 0) gbar(IS, 288, bx);  // B2: mh1 global
  __syncthreads();

  // ---- rs1b: per-channel rf -> IS[7] ----
  if (bx < 256 && tid == 0) {
    float sx = sc_slot(IS, 0);
    float sw1 = sc_slot(IS, 1);
    int mh1 = __hip_atomic_load(IS + 4, __ATOMIC_RELAXED, __HIP_MEMORY_SCOPE_AGENT);
    float sxw = sx * sw1;
    float s_h1 = fmaxf(sxw * (float)mh1 / 127.0f, 1e-8f);
    float wq = wq1[bx], bbc = b1[bx];
    float q1 = clamp8f(rintf((float)sVmax * sxw / s_h1));
    float q0 = clamp8f(rintf((float)sVmin * sxw / s_h1));
    float y1 = fmaxf(q1 * s_h1 * wq + bbc, 0.0f);
    float y0 = fmaxf(q0 * s_h1 * wq + bbc, 0.0f);
    atomicMax(IS + 7, __float_as_int(fmaxf(y1, y0)));  // rf >= 0
  }
  __syncthreads();
  if (tid == 0) gbar(IS, 448, bx);  // B3: rf global
  __syncthreads();

  // ---- scales, all local (no SC persistence needed) ----
  if (tid == 0) {
    float sx = sc_slot(IS, 0);
    float sw1 = sc_slot(IS, 1);
    int mh1 = __hip_atomic_load(IS + 4, __ATOMIC_RELAXED, __HIP_MEMORY_SCOPE_AGENT);
    int mrf = __hip_atomic_load(IS + 7, __ATOMIC_RELAXED, __HIP_MEMORY_SCOPE_AGENT);
    float sxw = sx * sw1;
    sSxw = sxw;
    sSh1 = fmaxf(sxw * (float)mh1 / 127.0f, 1e-8f);
    float s_y2 = fmaxf(__int_as_float(mrf) / 127.0f, 1e-8f);
    sSy2 = s_y2;
    int mid = __hip_atomic_load(IS + 5, __ATOMIC_RELAXED, __HIP_MEMORY_SCOPE_AGENT);
    float swid = sc_slot(IS, 3);
    sSxwid = sx * swid;
    sSidq = fmaxf(sx * swid * (float)mid / 127.0f, 1e-8f);
    sSxw2 = s_y2 * sc_slot(IS, 2);
  }
  __syncthreads();

  // ---- qh1 from parked LDS -> A2 via AGENT stores (fresh region, no X8 alias) ----
  {
    const float sxw = sSxw, s_h1 = sSh1, s_y2 = sSy2;
#pragma unroll
    for (int k = 0; k < 7; ++k) {
      int i = tid + k * 256;  // < 1792
      int sp = i >> 5, c4i = i & 31;
      int mwp = sp >= 28 ? 1 : 0;
      int wo = sp - mwp * 28;
      int c0 = nh * 128 + c4i * 4;
      const int* pk = lds + sp * 130 + c4i * 4;
      unsigned r0 = (unsigned char)qact(pk[0], sxw, s_h1, s_y2, wq1[c0], b1[c0]);
      unsigned r1 = (unsigned char)qact(pk[1], sxw, s_h1, s_y2, wq1[c0 + 1], b1[c0 + 1]);
      unsigned r2 = (unsigned char)qact(pk[2], sxw, s_h1, s_y2, wq1[c0 + 2], b1[c0 + 2]);
      unsigned r3 = (unsigned char)qact(pk[3], sxw, s_h1, s_y2, wq1[c0 + 3], b1[c0 + 3]);
      __hip_atomic_store(A2p + ((n * 28 + ho0 + mwp) * 28 + wo) * 64 + nh * 32 + c4i,
                         (int)(r0 | (r1 << 8) | (r2 << 16) | (r3 << 24)), __ATOMIC_RELAXED,
                         __HIP_MEMORY_SCOPE_AGENT);
    }
  }
  __syncthreads();
  if (tid == 0) gbar(IS, 608, bx);  // B4: A2 global (halo rows from neighbor blocks)
  __syncthreads();

  // ---- stage2: A2 rows ho0-1..ho0+2 -> lds conv2 layout (plain vi4 loads; region was
  //      never read pre-B4 -> no stale L2 lines; agent stores landed at coherence point) ----
  for (int r = 0; r < 4; ++r) {
    int h = ho0 - 1 + r;
    int* dst = lds + r * 30 * 68;
    if (h >= 0 && h < 28) {
      const vi4* src = (const vi4*)(A2p + (n * 28 + h) * 28 * 64);
      for (int i4 = tid; i4 < 448; i4 += THREADS) {
        int col = i4 >> 4, c = (i4 & 15) * 4;
        *(vi4*)(dst + (col + 1) * 68 + c) = src[i4];
      }
      if (tid < 64) dst[tid] = 0;
      else if (tid >= 128 && tid < 192) dst[29 * 68 + (tid - 128)] = 0;
    } else {
      for (int i4 = tid; i4 < 510; i4 += THREADS) ((vi4*)dst)[i4] = zero;
    }
  }
  __syncthreads();

  // ---- conv2 3x3 s1 p1, 36 K-steps, ping-pong -> acc (conv1 acc dead after park) ----
#pragma unroll
  for (int mt = 0; mt < 2; ++mt)
#pragma unroll
    for (int ct = 0; ct < 4; ++ct) acc[mt][ct] = zero;
  const vi4* wbase2 = W2m + ctbase * 64 + lane;
#pragma unroll
  for (int ct = 0; ct < 4; ++ct) bA[ct] = wbase2[ct * 64];
  {
    const int ro = mw * 30;  // ks=0
    a0A = *(const vi4*)(lds + (ro + woc0) * 68 + choff);
    a1A = *(const vi4*)(lds + (ro + woc1) * 68 + choff);
  }
#pragma unroll 1
  for (int ks = 0; ks < 36; ks += 2) {
    {
      const int ksn = ks + 1;
      const int khn = (ksn >= 12) + (ksn >= 24);
      const int t2 = ksn - khn * 12;
      const int kwn = t2 >> 2, kcn = t2 & 3;
#pragma unroll
      for (int ct = 0; ct < 4; ++ct) bB[ct] = wbase2[ksn * 1024 + ct * 64];
      const int ro = (mw + khn) * 30;
      a0B = *(const vi4*)(lds + (ro + woc0 + kwn) * 68 + kcn * 16 + choff);
      a1B = *(const vi4*)(lds + (ro + woc1 + kwn) * 68 + kcn * 16 + choff);
    }
#pragma unroll
    for (int ct = 0; ct < 4; ++ct) {
      acc[0][ct] = MFMA_I8(a0A, bA[ct], acc[0][ct]);
      acc[1][ct] = MFMA_I8(a1A, bA[ct], acc[1][ct]);
    }
    if (ks + 2 < 36) {
      const int ksn = ks + 2;
      const int khn = (ksn >= 12) + (ksn >= 24);
      const int t2 = ksn - khn * 12;
      const int kwn = t2 >> 2, kcn = t2 & 3;
#pragma unroll
      for (int ct = 0; ct < 4; ++ct) bA[ct] = wbase2[ksn * 1024 + ct * 64];
      const int ro = (mw + khn) * 30;
      a0A = *(const vi4*)(lds + (ro + woc0 + kwn) * 68 + kcn * 16 + choff);
      a1A = *(const vi4*)(lds + (ro + woc1 + kwn) * 68 + kcn * 16 + choff);
    }
#pragma unroll
    for (int ct = 0; ct < 4; ++ct) {
      acc[0][ct] = MFMA_I8(a0B, bB[ct], acc[0][ct]);
      acc[1][ct] = MFMA_I8(a1B, bB[ct], acc[1][ct]);
    }
  }

  // ---- block max|h2| straight from acc (H2 never stored) ----
  int am2 = 0;
#pragma unroll
  for (int ct = 0; ct < 4; ++ct)
#pragma unroll
    for (int mt = 0; mt < 2; ++mt)
#pragma unroll
      for (int r = 0; r < 4; ++r) {
        int wo = mt * 16 + quad * 4 + r;
        if (wo < 28) {
          int v = acc[mt][ct][r];
          am2 = max(am2, v < 0 ? -v : v);
        }
      }
#pragma unroll
  for (int k = 32; k >= 1; k >>= 1) am2 = max(am2, __shfl_xor(am2, k));
  if (lane == 0) redH[wv] = am2;
  __syncthreads();  // conv2 LDS reads done; redH visible
  if (tid == 0) {
    atomicMax(IS + 6, max(max(redH[0], redH[1]), max(redH[2], redH[3])));
    gbar(IS, 768, bx);  // B5: max|h2| global
    sMh2 = __hip_atomic_load(IS + 6, __ATOMIC_RELAXED, __HIP_MEMORY_SCOPE_SYSTEM);
  }
  __syncthreads();

  SumParams P;
  P.sxw2 = sSxw2;
  P.s_h2 = fmaxf(sSxw2 * (float)sMh2 / 127.0f, 1e-8f);
  P.sxwid = sSxwid;
  P.s_idq = sSidq;

  // ---- residual: identity comes STRAIGHT FROM accI registers (same (wo,co,row) mapping) ----
  float* sums = (float*)lds;  // [128][57], overwrites conv2 staging (dead)
  float fm = 0.0f;
#pragma unroll
  for (int ct = 0; ct < 4; ++ct) {
    const int co = (ctbase + ct) * 16 + lm;
    const int cl = co - nh * 128;
    float w2c = wq2[co], b2c = b2[co], wic = wqid[co], bic = bidp[co];
#pragma unroll
    for (int mt = 0; mt < 2; ++mt)
#pragma unroll
      for (int r = 0; r < 4; ++r) {
        int wo = mt * 16 + quad * 4 + r;
        if (wo < 28) {
          int slot = cl * 57 + mw * 28 + wo;
          float sv = sum_val(acc[mt][ct][r], accI[mt][ct][r], P, w2c, b2c, wic, bic);
          sums[slot] = sv;
          fm = fmaxf(fm, fabsf(sv));
        }
      }
  }
#pragma unroll
  for (int k = 32; k >= 1; k >>= 1) fm = fmaxf(fm, __shfl_xor(fm, k));
  if (lane == 0) redF[wv] = fm;
  __syncthreads();
  if (tid == 0) {
    float a = fmaxf(fmaxf(redF[0], redF[1]), fmaxf(redF[2], redF[3]));
    atomicMax(IS + 11, __float_as_int(a));
    gbar(IS, 928, bx);  // B6: max|sum| global
    int mb = __hip_atomic_load(IS + 11, __ATOMIC_RELAXED, __HIP_MEMORY_SCOPE_SYSTEM);
    sOutS = fmaxf(__int_as_float(mb) / 127.0f, 1e-8f);
  }
  __syncthreads();
  const float out_s = sOutS;

  // ---- requant + relu, NCHW write ----
  float* ob = out + n * 200704 + (nh * 128) * 784 + ho0 * 28;
#pragma unroll
  for (int k = 0; k < 28; ++k) {
    int idx = tid + k * 256;
    int cl = idx / 56, rem = idx % 56;
    float sv = sums[cl * 57 + rem];
    float q = clamp8f(rintf(sv / out_s));
    ob[cl * 784 + rem] = q > 0.0f ? q * out_s : 0.0f;
  }
  if (bx == 0 && tid == 0) out[6422528] = out_s;
}

extern "C" void kernel_launch(void* const* d_in, const int* in_sizes, int n_in, void* d_out,
                              int out_size, void* d_ws, size_t ws_size, hipStream_t stream) {
  (void)in_sizes; (void)n_in; (void)out_size; (void)ws_size;
  const float* x = (const float*)d_in[0];
  const float* w1 = (const float*)d_in[1];
  const float* w2 = (const float*)d_in[2];
  const float* wid = (const float*)d_in[3];
  const float* bn1g = (const float*)d_in[4];
  const float* bn1b = (const float*)d_in[5];
  const float* bn1m = (const float*)d_in[6];
  const float* bn1v = (const float*)d_in[7];
  const float* bn2g = (const float*)d_in[8];
  const float* bn2b = (const float*)d_in[9];
  const float* bn2m = (const float*)d_in[10];
  const float* bn2v = (const float*)d_in[11];
  const float* idg = (const float*)d_in[12];
  const float* idb = (const float*)d_in[13];
  const float* idm = (const float*)d_in[14];
  const float* idv = (const float*)d_in[15];

  char* ws = (char*)d_ws;
  int* IS = (int*)ws;
  unsigned* ISu = (unsigned*)ws;
  // barrier counters occupy IS[128..1088); per-channel tables after IS[1152]:
  float* wq1 = (float*)(ws + 4608);
  float* b1 = (float*)(ws + 5632);
  float* wq2 = (float*)(ws + 6656);
  float* b2 = (float*)(ws + 7680);
  float* wqid = (float*)(ws + 8704);
  float* bid = (float*)(ws + 9728);
  char* X8 = ws + 16384;  // NHWC int8 (read-only after k_quant; no A2 alias)
  char* W1m = X8 + 12845056;
  char* W2m = W1m + 294912;
  char* Widm = W2m + 589824;
  int* A2p = (int*)(Widm + 32768);  // A2 int8 as ints, fresh region
  float* out = (float*)d_out;
  int* maxS2 = (int*)d_out;  // extrema scratch in d_out (dead until k_ct's final out write)
  int* minS2 = maxS2 + 896 * 256;

  k_pre<<<723, THREADS, 0, stream>>>(IS, bn1g, bn1b, bn1m, bn1v, wq1, b1, bn2g, bn2b, bn2m, bn2v,
                                     wq2, b2, idg, idb, idm, idv, wqid, bid, (const float4*)w1,
                                     (const float4*)w2, (const float4*)wid, (const float4*)x);
  k_quant<<<2016, THREADS, 0, stream>>>(x, (int*)X8, w1, (vi4*)W1m, w2, (vi4*)W2m, wid,
                                        (vi4*)Widm, ISu);
  k_ct<<<GRID_BLOCKS, THREADS, 0, stream>>>((const int*)X8, (const vi4*)W1m, (const vi4*)Widm,
                                            (const vi4*)W2m, A2p, IS, wq1, b1, wq2, b2, wqid, bid,
                                            out, maxS2, minS2);
}